// Round 16
// baseline (58.021 us; speedup 1.0000x reference)
//
#include <hip/hip_runtime.h>

typedef unsigned long long u64;
typedef unsigned int u32;
typedef unsigned short u16;

#define N_DET 4096
#define NW 64               // 4096 bits = 64 u64 words
#define IOU_TR 0.3f
#define SCORE_TR 0.1f
#define EPS 1e-9f

// ---------------------------------------------------------------------------
// ws layout (R15):
//   rows  : 4096*8 f32    (sorted detection rows)        128 KB
//   ssc   : 4096 f32      (sorted scores, compact)        16 KB
//   soaLO : 4096 float4   (lox,loy,loz,vol)               64 KB
//   soaHI : 4096 float4   (hix,hiy,hiz,0)                 64 KB
//   A     : 64 u64        (bit i = row i nonempty)
//   keep  : 64 u64
//   Trm   : 4096*64 u64   row-major; nonempty rows written; row 4095 zeroed.
// 4 dispatches: k_sort, k_sup (float4, valid-skip), k_scan (BATCH-16
// parallel test + forward-only conflict check + serial redo), k_out.
// LEDGER: R15 57.5 best. Refuted: ov-branch sup (R7/R9), edge-walk (R11),
// 2-row sup (R12), mirror scan (R14), last-block fusion (R7/R13).
// Batch-16 rationale: masks are strictly forward (j>i) => no conflict hit
// implies parallel==serial exactly; redo path touches registers only.
// ---------------------------------------------------------------------------

__device__ __forceinline__ u64 rl64(u64 v, int l) {
    unsigned lo = __builtin_amdgcn_readlane((unsigned)v, l);
    unsigned hi = __builtin_amdgcn_readlane((unsigned)(v >> 32), l);
    return ((u64)hi << 32) | lo;
}

// K1: stable descending rank sort (R15-exact) + zero A + zero Trm row 4095.
__global__ void __launch_bounds__(256) k_sort(const float* __restrict__ res,
                                              float* __restrict__ rows,
                                              float* __restrict__ ssc,
                                              float4* __restrict__ soaLO,
                                              float4* __restrict__ soaHI,
                                              u64* __restrict__ A,
                                              u64* __restrict__ Trm) {
    __shared__ float s[N_DET];
    int tid = threadIdx.x;
    if (blockIdx.x == 0) {
        if (tid < 64) A[tid] = 0ull;
        if (tid >= 64 && tid < 128)                 // sentinel row: all zeros
            Trm[(size_t)4095 * NW + (tid - 64)] = 0ull;
    }
    for (int j = tid; j < N_DET; j += 256) s[j] = res[j * 8];
    __syncthreads();
    int r = tid >> 4, c = tid & 15;
    int gi = blockIdx.x * 16 + r;
    float sc = s[gi];
    int part = 0;
    int j0 = c * 256;
    for (int j = j0; j < j0 + 256; ++j) {
        float sj = s[j];
        part += (sj > sc) || (sj == sc && j < gi);
    }
    part += __shfl_xor(part, 1, 64);
    part += __shfl_xor(part, 2, 64);
    part += __shfl_xor(part, 4, 64);
    part += __shfl_xor(part, 8, 64);
    if (c == 0) {
        int rank = part;
        float4 a = *(const float4*)(res + gi * 8);
        float4 b = *(const float4*)(res + gi * 8 + 4);
        *(float4*)(rows + rank * 8)     = a;
        *(float4*)(rows + rank * 8 + 4) = b;
        ssc[rank] = a.x;
        // a = (score, class, cx, cy); b = (cz, dx, dy, dz)
        float cx = a.z, cy = a.w, cz = b.x, dx = b.y, dy = b.z, dz = b.w;
        soaLO[rank] = make_float4(cx - dx * 0.5f, cy - dy * 0.5f,
                                  cz - dz * 0.5f, (dx * dy) * dz); // vol in .w
        soaHI[rank] = make_float4(cx + dx * 0.5f, cy + dy * 0.5f,
                                  cz + dz * 0.5f, 0.0f);
    }
}

// K2: suppression rows (R15 float4 body) + wave-uniform invalid-row skip
// (invalid rows are never applied by the reference -> row content unused).
__global__ void k_sup(const float4* __restrict__ soaLO,
                      const float4* __restrict__ soaHI,
                      const float* __restrict__ ssc,
                      u64* __restrict__ Trm, u64* __restrict__ A) {
    int lane = threadIdx.x & 63;
    int wave = threadIdx.x >> 6;
    int i = blockIdx.x * 4 + wave;
    if (ssc[i] < SCORE_TR) return;                // wave-uniform, pre-loop
    float4 iLO = soaLO[i];                        // (lox,loy,loz,vol)
    float4 iHI = soaHI[i];                        // (hix,hiy,hiz,-)
    u64 rowword = 0, rowOr = 0;
    for (int w = (i >> 6); w < NW; ++w) {
        int j = w * 64 + lane;
        float4 jLO = soaLO[j];
        float4 jHI = soaHI[j];
        float ix = fminf(iHI.x, jHI.x) - fmaxf(iLO.x, jLO.x); ix = fmaxf(ix, 0.f);
        float iy = fminf(iHI.y, jHI.y) - fmaxf(iLO.y, jLO.y); iy = fmaxf(iy, 0.f);
        float iz = fminf(iHI.z, jHI.z) - fmaxf(iLO.z, jLO.z); iz = fmaxf(iz, 0.f);
        float inter = (ix * iy) * iz;             // ((x*y)*z) like np.prod
        float uni = iLO.w + jLO.w - inter;        // (vol_i+vol_j)-inter
        float iou = inter / (uni + EPS);          // IEEE div
        bool sb = (iou > IOU_TR) && (j > i);
        u64 m = __ballot(sb);
        rowOr |= m;
        rowword = (lane == w) ? m : rowword;
    }
    if (rowOr) {                                  // wave-uniform branch
        Trm[(size_t)i * NW + lane] = rowword;     // coalesced 512B store
        if (lane == 0) atomicOr(&A[i >> 6], 1ull << (i & 63));
    }
}

// K3: sparse greedy scan, BATCH-16.
#define FIDX(V, GB) { V = (u32)s_nlist[(GB) + (lane & 15)]; }

#define IS1(V, P, S) { u32 si_ = (u32)__builtin_amdgcn_readlane((V), (S)); \
    P##S = Trm[(size_t)si_ * NW + lane]; }

#define IS16(V, P) IS1(V,P,0) IS1(V,P,1) IS1(V,P,2) IS1(V,P,3)   \
    IS1(V,P,4) IS1(V,P,5) IS1(V,P,6) IS1(V,P,7)                  \
    IS1(V,P,8) IS1(V,P,9) IS1(V,P,10) IS1(V,P,11)                \
    IS1(V,P,12) IS1(V,P,13) IS1(V,P,14) IS1(V,P,15)

// Parallel test vs batch-entry act; accumulate applied (per-lane u64).
#define TA1(V, P, S) { u32 si_ = (u32)__builtin_amdgcn_readlane((V), (S)); \
    u64 aw_ = rl64(act, (int)(si_ >> 6));                                  \
    u64 m_ = 0ull - ((aw_ >> (si_ & 63u)) & 1ull);                         \
    applied |= ((P##S) & m_); }

// Conflict: did applied hit any batch-row position? (forward-only masks =>
// a hit can only come from an earlier co-batch row => redo needed.)
#define TC1(V, S) { u32 si_ = (u32)__builtin_amdgcn_readlane((V), (S)); \
    u64 aw_ = rl64(applied, (int)(si_ >> 6));                           \
    cfl |= (aw_ >> (si_ & 63u)) & 1ull; }

// Serial fallback (exact; Trm row 4095 zeroed -> sentinels are no-ops).
#define PR1(V, P, S) { u32 si_ = (u32)__builtin_amdgcn_readlane((V), (S)); \
    u64 awd_ = rl64(act, (int)(si_ >> 6));                                 \
    u64 m_ = 0ull - ((awd_ >> (si_ & 63u)) & 1ull);                        \
    act &= ~(P##S & m_); }

#define BATCH16(V, P) { \
    u64 applied = 0ull, cfl = 0ull; \
    TA1(V,P,0)  TA1(V,P,1)  TA1(V,P,2)  TA1(V,P,3)  \
    TA1(V,P,4)  TA1(V,P,5)  TA1(V,P,6)  TA1(V,P,7)  \
    TA1(V,P,8)  TA1(V,P,9)  TA1(V,P,10) TA1(V,P,11) \
    TA1(V,P,12) TA1(V,P,13) TA1(V,P,14) TA1(V,P,15) \
    TC1(V,0)  TC1(V,1)  TC1(V,2)  TC1(V,3)  \
    TC1(V,4)  TC1(V,5)  TC1(V,6)  TC1(V,7)  \
    TC1(V,8)  TC1(V,9)  TC1(V,10) TC1(V,11) \
    TC1(V,12) TC1(V,13) TC1(V,14) TC1(V,15) \
    if (cfl) {                      /* uniform, rare: exact serial redo */ \
        PR1(V,P,0)  PR1(V,P,1)  PR1(V,P,2)  PR1(V,P,3)  \
        PR1(V,P,4)  PR1(V,P,5)  PR1(V,P,6)  PR1(V,P,7)  \
        PR1(V,P,8)  PR1(V,P,9)  PR1(V,P,10) PR1(V,P,11) \
        PR1(V,P,12) PR1(V,P,13) PR1(V,P,14) PR1(V,P,15) \
    } else { \
        act &= ~applied; } }

__global__ void __launch_bounds__(256, 1)
k_scan(const u64* __restrict__ Trm, const u64* __restrict__ A,
       const float* __restrict__ ssc, u64* __restrict__ keep) {
    __shared__ u64 s_valid[NW];
    __shared__ u16 s_nlist[4224];
    const int tid = threadIdx.x;
    const int wv = tid >> 6;
    const int lane = tid & 63;

    for (int w = wv * 16; w < wv * 16 + 16; ++w) {
        float scw = ssc[w * 64 + lane];            // coalesced
        u64 m = __ballot(scw >= SCORE_TR);
        if (lane == 0) s_valid[w] = m;
    }
    __syncthreads();
    if (wv != 0) return;

    u64 act = s_valid[lane];
    u64 avA = A[lane] & act;           // nonempty AND valid (invalid = no-op)
    int pc = __popcll(avA);
    int inc = pc;
#pragma unroll
    for (int d = 1; d < 64; d <<= 1) {
        int t = __shfl_up(inc, d, 64);
        if (lane >= d) inc += t;
    }
    int exc = inc - pc;
    int nTotal = __shfl(inc, 63, 64);
    {   // emit this lane's active-row indices (globally sorted)
        u64 m = avA; int o = exc;
        while (m) {
            int k = __builtin_ctzll(m); m &= m - 1;
            s_nlist[o++] = (u16)(lane * 64 + k);
        }
    }
    int padded = (nTotal + 63) & ~63;
    for (int t = nTotal + lane; t < padded + 128; t += 64)
        s_nlist[t] = (u16)4095;            // sentinel (Trm row 4095 zeroed)
    __threadfence_block();                 // wave-local LDS ordering

    if (padded > 0) {
        u64 pa0,pa1,pa2,pa3,pa4,pa5,pa6,pa7,
            pa8,pa9,pa10,pa11,pa12,pa13,pa14,pa15;
        u64 pb0,pb1,pb2,pb3,pb4,pb5,pb6,pb7,
            pb8,pb9,pb10,pb11,pb12,pb13,pb14,pb15;
        u32 iA0, iA1, iB0, iB1;
        FIDX(iA0, 0)  IS16(iA0, pa)
        FIDX(iB0, 16) IS16(iB0, pb)
        int g = 0;
        while (g < padded) {
            FIDX(iA1, g + 32)
            BATCH16(iA0, pa)               // rows g..g+15
            IS16(iA1, pa)                  // issue g+32
            FIDX(iB1, g + 48)
            BATCH16(iB0, pb)               // rows g+16..g+31
            IS16(iB1, pb)                  // issue g+48
            g += 32;
            if (g >= padded) break;
            FIDX(iA0, g + 32)
            BATCH16(iA1, pa)
            IS16(iA0, pa)
            FIDX(iB0, g + 48)
            BATCH16(iB1, pb)
            IS16(iB0, pb)
            g += 32;
        }
    }
    keep[lane] = act;                      // final act == keep mask
}

// K4: gated output, 16 blocks x 256 threads, coalesced (R15 exact).
__global__ void k_out(const float* __restrict__ rows,
                      const u64* __restrict__ keep,
                      float* __restrict__ out) {
    int i = blockIdx.x * 256 + threadIdx.x;
    bool kp = (keep[i >> 6] >> (i & 63)) & 1ull;
    float4 a = kp ? ((const float4*)rows)[i * 2]     : make_float4(0.f, 0.f, 0.f, 0.f);
    float4 b = kp ? ((const float4*)rows)[i * 2 + 1] : make_float4(0.f, 0.f, 0.f, 0.f);
    ((float4*)out)[i * 2]     = a;
    ((float4*)out)[i * 2 + 1] = b;
}

extern "C" void kernel_launch(void* const* d_in, const int* in_sizes, int n_in,
                              void* d_out, int out_size, void* d_ws, size_t ws_size,
                              hipStream_t stream) {
    const float* res = (const float*)d_in[0];
    float* out = (float*)d_out;

    float*  rows  = (float*)d_ws;                     // 32768 f32
    float*  ssc   = rows + N_DET * 8;                 // 4096 f32
    float4* soaLO = (float4*)(ssc + N_DET);           // 4096 float4
    float4* soaHI = soaLO + N_DET;                    // 4096 float4
    u64*    A     = (u64*)(soaHI + N_DET);            // 64 u64
    u64*    keep  = A + NW;                           // 64 u64
    u64*    Trm   = keep + NW;                        // 4096*64 u64

    k_sort<<<N_DET / 16, 256, 0, stream>>>(res, rows, ssc, soaLO, soaHI, A, Trm);
    k_sup <<<N_DET / 4, 256, 0, stream>>>(soaLO, soaHI, ssc, Trm, A);
    k_scan<<<1, 256, 0, stream>>>(Trm, A, ssc, keep);
    k_out <<<16, 256, 0, stream>>>(rows, keep, out);
}

// Round 17
// 55.314 us; speedup vs baseline: 1.0489x; 1.0489x over previous
//
#include <hip/hip_runtime.h>

typedef unsigned long long u64;
typedef unsigned int u32;
typedef unsigned short u16;

#define N_DET 4096
#define NW 64               // 4096 bits = 64 u64 words
#define IOU_TR 0.3f
#define SCORE_TR 0.1f
#define EPS 1e-9f

// ---------------------------------------------------------------------------
// ws layout (R15):
//   rows  : 4096*8 f32    (sorted detection rows)        128 KB
//   ssc   : 4096 f32      (sorted scores, compact)        16 KB
//   soaLO : 4096 float4   (lox,loy,loz,vol)               64 KB
//   soaHI : 4096 float4   (hix,hiy,hiz,0)                 64 KB
//   A     : 64 u64        (bit i = row i nonempty)
//   keep  : 64 u64
//   Trm   : 4096*64 u64   row-major; nonempty rows written; row 4095 zeroed.
// 4 dispatches: k_sort, k_sup, k_scan (serial PR chain, 4-BATCH / 64-row
// prefetch pipeline — this round's single variable), k_out.
// LEDGER: R15 57.5 best; R16 batch-16 neutral => scan is NOT chain-bound;
// measured fusion data (R10>R8) => gaps ~3µs => scan ≈ 30µs => latency-bound
// on Trm gathers with only 2-batch lookahead. This round: depth 2 -> 4.
// Refuted: ov-branch sup (R7/R9), edge-walk (R11), 2-row sup (R12), mirror
// scan (R14), last-block fusion (R7/R13), batch-16 parallel test (R16).
// ---------------------------------------------------------------------------

__device__ __forceinline__ u64 rl64(u64 v, int l) {
    unsigned lo = __builtin_amdgcn_readlane((unsigned)v, l);
    unsigned hi = __builtin_amdgcn_readlane((unsigned)(v >> 32), l);
    return ((u64)hi << 32) | lo;
}

// K1: stable descending rank sort (R15-exact) + zero A + zero Trm row 4095.
__global__ void __launch_bounds__(256) k_sort(const float* __restrict__ res,
                                              float* __restrict__ rows,
                                              float* __restrict__ ssc,
                                              float4* __restrict__ soaLO,
                                              float4* __restrict__ soaHI,
                                              u64* __restrict__ A,
                                              u64* __restrict__ Trm) {
    __shared__ float s[N_DET];
    int tid = threadIdx.x;
    if (blockIdx.x == 0) {
        if (tid < 64) A[tid] = 0ull;
        if (tid >= 64 && tid < 128)                 // sentinel row: all zeros
            Trm[(size_t)4095 * NW + (tid - 64)] = 0ull;
    }
    for (int j = tid; j < N_DET; j += 256) s[j] = res[j * 8];
    __syncthreads();
    int r = tid >> 4, c = tid & 15;
    int gi = blockIdx.x * 16 + r;
    float sc = s[gi];
    int part = 0;
    int j0 = c * 256;
    for (int j = j0; j < j0 + 256; ++j) {
        float sj = s[j];
        part += (sj > sc) || (sj == sc && j < gi);
    }
    part += __shfl_xor(part, 1, 64);
    part += __shfl_xor(part, 2, 64);
    part += __shfl_xor(part, 4, 64);
    part += __shfl_xor(part, 8, 64);
    if (c == 0) {
        int rank = part;
        float4 a = *(const float4*)(res + gi * 8);
        float4 b = *(const float4*)(res + gi * 8 + 4);
        *(float4*)(rows + rank * 8)     = a;
        *(float4*)(rows + rank * 8 + 4) = b;
        ssc[rank] = a.x;
        // a = (score, class, cx, cy); b = (cz, dx, dy, dz)
        float cx = a.z, cy = a.w, cz = b.x, dx = b.y, dy = b.z, dz = b.w;
        soaLO[rank] = make_float4(cx - dx * 0.5f, cy - dy * 0.5f,
                                  cz - dz * 0.5f, (dx * dy) * dz); // vol in .w
        soaHI[rank] = make_float4(cx + dx * 0.5f, cy + dy * 0.5f,
                                  cz + dz * 0.5f, 0.0f);
    }
}

// K2: suppression rows (R15 float4 body) + wave-uniform invalid-row skip.
__global__ void k_sup(const float4* __restrict__ soaLO,
                      const float4* __restrict__ soaHI,
                      const float* __restrict__ ssc,
                      u64* __restrict__ Trm, u64* __restrict__ A) {
    int lane = threadIdx.x & 63;
    int wave = threadIdx.x >> 6;
    int i = blockIdx.x * 4 + wave;
    if (ssc[i] < SCORE_TR) return;                // wave-uniform, pre-loop
    float4 iLO = soaLO[i];                        // (lox,loy,loz,vol)
    float4 iHI = soaHI[i];                        // (hix,hiy,hiz,-)
    u64 rowword = 0, rowOr = 0;
    for (int w = (i >> 6); w < NW; ++w) {
        int j = w * 64 + lane;
        float4 jLO = soaLO[j];
        float4 jHI = soaHI[j];
        float ix = fminf(iHI.x, jHI.x) - fmaxf(iLO.x, jLO.x); ix = fmaxf(ix, 0.f);
        float iy = fminf(iHI.y, jHI.y) - fmaxf(iLO.y, jLO.y); iy = fmaxf(iy, 0.f);
        float iz = fminf(iHI.z, jHI.z) - fmaxf(iLO.z, jLO.z); iz = fmaxf(iz, 0.f);
        float inter = (ix * iy) * iz;             // ((x*y)*z) like np.prod
        float uni = iLO.w + jLO.w - inter;        // (vol_i+vol_j)-inter
        float iou = inter / (uni + EPS);          // IEEE div
        bool sb = (iou > IOU_TR) && (j > i);
        u64 m = __ballot(sb);
        rowOr |= m;
        rowword = (lane == w) ? m : rowword;
    }
    if (rowOr) {                                  // wave-uniform branch
        Trm[(size_t)i * NW + lane] = rowword;     // coalesced 512B store
        if (lane == 0) atomicOr(&A[i >> 6], 1ull << (i & 63));
    }
}

// K3: sparse greedy scan, serial PR chain, 4-batch (64-row) prefetch.
#define FIDX(V, GB) { V = (u32)s_nlist[(GB) + (lane & 15)]; }

#define IS1(V, P, S) { u32 si_ = (u32)__builtin_amdgcn_readlane((V), (S)); \
    P##S = Trm[(size_t)si_ * NW + lane]; }

#define IS16(V, P) IS1(V,P,0) IS1(V,P,1) IS1(V,P,2) IS1(V,P,3)   \
    IS1(V,P,4) IS1(V,P,5) IS1(V,P,6) IS1(V,P,7)                  \
    IS1(V,P,8) IS1(V,P,9) IS1(V,P,10) IS1(V,P,11)                \
    IS1(V,P,12) IS1(V,P,13) IS1(V,P,14) IS1(V,P,15)

// Serial row step (exact; Trm row 4095 zeroed -> sentinels are no-ops).
#define PR1(V, P, S) { u32 si_ = (u32)__builtin_amdgcn_readlane((V), (S)); \
    u64 awd_ = rl64(act, (int)(si_ >> 6));                                 \
    u64 m_ = 0ull - ((awd_ >> (si_ & 63u)) & 1ull);                        \
    act &= ~(P##S & m_); }

#define PR16(V, P) PR1(V,P,0) PR1(V,P,1) PR1(V,P,2) PR1(V,P,3)   \
    PR1(V,P,4) PR1(V,P,5) PR1(V,P,6) PR1(V,P,7)                  \
    PR1(V,P,8) PR1(V,P,9) PR1(V,P,10) PR1(V,P,11)                \
    PR1(V,P,12) PR1(V,P,13) PR1(V,P,14) PR1(V,P,15)

__global__ void __launch_bounds__(256, 1)
k_scan(const u64* __restrict__ Trm, const u64* __restrict__ A,
       const float* __restrict__ ssc, u64* __restrict__ keep) {
    __shared__ u64 s_valid[NW];
    __shared__ u16 s_nlist[4352];
    const int tid = threadIdx.x;
    const int wv = tid >> 6;
    const int lane = tid & 63;

    for (int w = wv * 16; w < wv * 16 + 16; ++w) {
        float scw = ssc[w * 64 + lane];            // coalesced
        u64 m = __ballot(scw >= SCORE_TR);
        if (lane == 0) s_valid[w] = m;
    }
    __syncthreads();
    if (wv != 0) return;

    u64 act = s_valid[lane];
    u64 avA = A[lane] & act;           // nonempty AND valid (invalid = no-op)
    int pc = __popcll(avA);
    int inc = pc;
#pragma unroll
    for (int d = 1; d < 64; d <<= 1) {
        int t = __shfl_up(inc, d, 64);
        if (lane >= d) inc += t;
    }
    int exc = inc - pc;
    int nTotal = __shfl(inc, 63, 64);
    {   // emit this lane's active-row indices (globally sorted)
        u64 m = avA; int o = exc;
        while (m) {
            int k = __builtin_ctzll(m); m &= m - 1;
            s_nlist[o++] = (u16)(lane * 64 + k);
        }
    }
    int padded = (nTotal + 63) & ~63;
    for (int t = nTotal + lane; t < padded + 192; t += 64)
        s_nlist[t] = (u16)4095;            // sentinel (Trm row 4095 zeroed)
    __threadfence_block();                 // wave-local LDS ordering

    if (padded > 0) {
        u64 pa0,pa1,pa2,pa3,pa4,pa5,pa6,pa7,
            pa8,pa9,pa10,pa11,pa12,pa13,pa14,pa15;
        u64 pb0,pb1,pb2,pb3,pb4,pb5,pb6,pb7,
            pb8,pb9,pb10,pb11,pb12,pb13,pb14,pb15;
        u64 pc0,pc1,pc2,pc3,pc4,pc5,pc6,pc7,
            pc8,pc9,pc10,pc11,pc12,pc13,pc14,pc15;
        u64 pd0,pd1,pd2,pd3,pd4,pd5,pd6,pd7,
            pd8,pd9,pd10,pd11,pd12,pd13,pd14,pd15;
        u32 iA, iB, iC, iD;
        // prefill 3 batches (48-row lookahead at steady state = 4 in flight)
        FIDX(iA, 0)  IS16(iA, pa)
        FIDX(iB, 16) IS16(iB, pb)
        FIDX(iC, 32) IS16(iC, pc)
        int g = 0;
        while (g < padded) {
            FIDX(iD, g + 48)  PR16(iA, pa)  IS16(iD, pd)
            FIDX(iA, g + 64)  PR16(iB, pb)  IS16(iA, pa)
            FIDX(iB, g + 80)  PR16(iC, pc)  IS16(iB, pb)
            FIDX(iC, g + 96)  PR16(iD, pd)  IS16(iC, pc)
            g += 64;
        }
    }
    keep[lane] = act;                      // final act == keep mask
}

// K4: gated output, 16 blocks x 256 threads, coalesced (R15 exact).
__global__ void k_out(const float* __restrict__ rows,
                      const u64* __restrict__ keep,
                      float* __restrict__ out) {
    int i = blockIdx.x * 256 + threadIdx.x;
    bool kp = (keep[i >> 6] >> (i & 63)) & 1ull;
    float4 a = kp ? ((const float4*)rows)[i * 2]     : make_float4(0.f, 0.f, 0.f, 0.f);
    float4 b = kp ? ((const float4*)rows)[i * 2 + 1] : make_float4(0.f, 0.f, 0.f, 0.f);
    ((float4*)out)[i * 2]     = a;
    ((float4*)out)[i * 2 + 1] = b;
}

extern "C" void kernel_launch(void* const* d_in, const int* in_sizes, int n_in,
                              void* d_out, int out_size, void* d_ws, size_t ws_size,
                              hipStream_t stream) {
    const float* res = (const float*)d_in[0];
    float* out = (float*)d_out;

    float*  rows  = (float*)d_ws;                     // 32768 f32
    float*  ssc   = rows + N_DET * 8;                 // 4096 f32
    float4* soaLO = (float4*)(ssc + N_DET);           // 4096 float4
    float4* soaHI = soaLO + N_DET;                    // 4096 float4
    u64*    A     = (u64*)(soaHI + N_DET);            // 64 u64
    u64*    keep  = A + NW;                           // 64 u64
    u64*    Trm   = keep + NW;                        // 4096*64 u64

    k_sort<<<N_DET / 16, 256, 0, stream>>>(res, rows, ssc, soaLO, soaHI, A, Trm);
    k_sup <<<N_DET / 4, 256, 0, stream>>>(soaLO, soaHI, ssc, Trm, A);
    k_scan<<<1, 256, 0, stream>>>(Trm, A, ssc, keep);
    k_out <<<16, 256, 0, stream>>>(rows, keep, out);
}

// Round 18
// 52.500 us; speedup vs baseline: 1.1051x; 1.0536x over previous
//
#include <hip/hip_runtime.h>

typedef unsigned long long u64;
typedef unsigned int u32;
typedef unsigned short u16;

#define N_DET 4096
#define NW 64               // 4096 bits = 64 u64 words
#define IOU_TR 0.3f
#define SCORE_TR 0.1f
#define EPS 1e-9f

// ---------------------------------------------------------------------------
// ws layout (R15/R17):
//   rows  : 4096*8 f32    (sorted detection rows)        128 KB
//   ssc   : 4096 f32      (sorted scores, compact)        16 KB
//   soaLO : 4096 float4   (lox,loy,loz,vol)               64 KB
//   soaHI : 4096 float4   (hix,hiy,hiz,0)                 64 KB
//   A     : 64 u64        (bit i = row i nonempty)
//   keep  : 64 u64
//   Trm   : 4096*64 u64   row-major; nonempty rows written; row 4095 zeroed.
// 4 dispatches: k_sort, k_sup, k_scan (PRODUCER-CONSUMER: waves 1-3 gather
// 48 rows/super-batch into double-buffered LDS, wave 0 runs the serial PR
// chain from LDS; __syncthreads pipeline), k_out.
// LEDGER: R17 55.3 best (4-deep prefetch -2.2 => latency-concurrency bound).
// Refuted: ov-branch sup (R7/R9), edge-walk (R11), 2-row sup (R12), mirror
// scan (R14), last-block fusion (R7/R13), batch-16 parallel test (R16).
// ---------------------------------------------------------------------------

__device__ __forceinline__ u64 rl64(u64 v, int l) {
    unsigned lo = __builtin_amdgcn_readlane((unsigned)v, l);
    unsigned hi = __builtin_amdgcn_readlane((unsigned)(v >> 32), l);
    return ((u64)hi << 32) | lo;
}

// K1: stable descending rank sort (R17-exact) + zero A + zero Trm row 4095.
__global__ void __launch_bounds__(256) k_sort(const float* __restrict__ res,
                                              float* __restrict__ rows,
                                              float* __restrict__ ssc,
                                              float4* __restrict__ soaLO,
                                              float4* __restrict__ soaHI,
                                              u64* __restrict__ A,
                                              u64* __restrict__ Trm) {
    __shared__ float s[N_DET];
    int tid = threadIdx.x;
    if (blockIdx.x == 0) {
        if (tid < 64) A[tid] = 0ull;
        if (tid >= 64 && tid < 128)                 // sentinel row: all zeros
            Trm[(size_t)4095 * NW + (tid - 64)] = 0ull;
    }
    for (int j = tid; j < N_DET; j += 256) s[j] = res[j * 8];
    __syncthreads();
    int r = tid >> 4, c = tid & 15;
    int gi = blockIdx.x * 16 + r;
    float sc = s[gi];
    int part = 0;
    int j0 = c * 256;
    for (int j = j0; j < j0 + 256; ++j) {
        float sj = s[j];
        part += (sj > sc) || (sj == sc && j < gi);
    }
    part += __shfl_xor(part, 1, 64);
    part += __shfl_xor(part, 2, 64);
    part += __shfl_xor(part, 4, 64);
    part += __shfl_xor(part, 8, 64);
    if (c == 0) {
        int rank = part;
        float4 a = *(const float4*)(res + gi * 8);
        float4 b = *(const float4*)(res + gi * 8 + 4);
        *(float4*)(rows + rank * 8)     = a;
        *(float4*)(rows + rank * 8 + 4) = b;
        ssc[rank] = a.x;
        // a = (score, class, cx, cy); b = (cz, dx, dy, dz)
        float cx = a.z, cy = a.w, cz = b.x, dx = b.y, dy = b.z, dz = b.w;
        soaLO[rank] = make_float4(cx - dx * 0.5f, cy - dy * 0.5f,
                                  cz - dz * 0.5f, (dx * dy) * dz); // vol in .w
        soaHI[rank] = make_float4(cx + dx * 0.5f, cy + dy * 0.5f,
                                  cz + dz * 0.5f, 0.0f);
    }
}

// K2: suppression rows (R17-exact: float4 body + wave-uniform invalid skip).
__global__ void k_sup(const float4* __restrict__ soaLO,
                      const float4* __restrict__ soaHI,
                      const float* __restrict__ ssc,
                      u64* __restrict__ Trm, u64* __restrict__ A) {
    int lane = threadIdx.x & 63;
    int wave = threadIdx.x >> 6;
    int i = blockIdx.x * 4 + wave;
    if (ssc[i] < SCORE_TR) return;                // wave-uniform, pre-loop
    float4 iLO = soaLO[i];                        // (lox,loy,loz,vol)
    float4 iHI = soaHI[i];                        // (hix,hiy,hiz,-)
    u64 rowword = 0, rowOr = 0;
    for (int w = (i >> 6); w < NW; ++w) {
        int j = w * 64 + lane;
        float4 jLO = soaLO[j];
        float4 jHI = soaHI[j];
        float ix = fminf(iHI.x, jHI.x) - fmaxf(iLO.x, jLO.x); ix = fmaxf(ix, 0.f);
        float iy = fminf(iHI.y, jHI.y) - fmaxf(iLO.y, jLO.y); iy = fmaxf(iy, 0.f);
        float iz = fminf(iHI.z, jHI.z) - fmaxf(iLO.z, jLO.z); iz = fmaxf(iz, 0.f);
        float inter = (ix * iy) * iz;             // ((x*y)*z) like np.prod
        float uni = iLO.w + jLO.w - inter;        // (vol_i+vol_j)-inter
        float iou = inter / (uni + EPS);          // IEEE div
        bool sb = (iou > IOU_TR) && (j > i);
        u64 m = __ballot(sb);
        rowOr |= m;
        rowword = (lane == w) ? m : rowword;
    }
    if (rowOr) {                                  // wave-uniform branch
        Trm[(size_t)i * NW + lane] = rowword;     // coalesced 512B store
        if (lane == 0) atomicOr(&A[i >> 6], 1ull << (i & 63));
    }
}

// K3: sparse greedy scan, producer-consumer. Waves 1-3 each stage 16 rows
// per super-batch (48 rows, 24 KB) into a double-buffered LDS ring; wave 0
// consumes via the proven serial PR chain (LDS reads, ~120cyc, fully hidden).
// One __syncthreads per super-batch; block-uniform control flow throughout.
__global__ void __launch_bounds__(256, 1)
k_scan(const u64* __restrict__ Trm, const u64* __restrict__ A,
       const float* __restrict__ ssc, u64* __restrict__ keep) {
    __shared__ u64 s_valid[NW];
    __shared__ u16 s_nlist[4608];
    __shared__ int s_nsb;
    __shared__ u64 sbuf[2][48][64];    // 48 KB double buffer
    const int tid = threadIdx.x;
    const int wv = tid >> 6;
    const int lane = tid & 63;

    // valid ballots over compact scores: 4 waves x 16 words
    for (int w = wv * 16; w < wv * 16 + 16; ++w) {
        float scw = ssc[w * 64 + lane];            // coalesced
        u64 m = __ballot(scw >= SCORE_TR);
        if (lane == 0) s_valid[w] = m;
    }
    __syncthreads();

    // wave 0: build globally-sorted active-row list + sentinel padding
    if (wv == 0) {
        u64 avA = A[lane] & s_valid[lane];  // nonempty AND valid
        int pc = __popcll(avA);
        int inc = pc;
#pragma unroll
        for (int d = 1; d < 64; d <<= 1) {
            int t = __shfl_up(inc, d, 64);
            if (lane >= d) inc += t;
        }
        int exc = inc - pc;
        int nTotal = __shfl(inc, 63, 64);
        u64 m = avA; int o = exc;
        while (m) {
            int k = __builtin_ctzll(m); m &= m - 1;
            s_nlist[o++] = (u16)(lane * 64 + k);
        }
        int nSB = (nTotal + 47) / 48;
        for (int t = nTotal + lane; t < (nSB + 1) * 48; t += 64)
            s_nlist[t] = (u16)4095;        // sentinel (Trm row 4095 zeroed)
        if (lane == 0) s_nsb = nSB;
    }
    __syncthreads();

    const int nSB = s_nsb;
    // prologue: loader waves fill buffer 0 with super-batch 0
    if (wv > 0 && nSB > 0) {
        const int base = (wv - 1) * 16;
#pragma unroll
        for (int s = 0; s < 16; ++s) {
            u32 si = (u32)s_nlist[base + s];
            sbuf[0][base + s][lane] = Trm[(size_t)si * NW + lane];
        }
    }
    u64 act = s_valid[lane];
    __syncthreads();

    for (int t = 0; t < nSB; ++t) {        // uniform bound, uniform barriers
        const int cur = t & 1;
        if (wv > 0) {                      // producers: stage super-batch t+1
            const int base = (wv - 1) * 16;
            const int off = (t + 1) * 48 + base;
#pragma unroll
            for (int s = 0; s < 16; ++s) {
                u32 si = (u32)s_nlist[off + s];
                sbuf[cur ^ 1][base + s][lane] = Trm[(size_t)si * NW + lane];
            }
        } else {                           // consumer: serial PR chain on LDS
            const int off = t * 48;
#pragma unroll
            for (int s = 0; s < 48; ++s) {
                u32 siv = (u32)s_nlist[off + s];
                u32 si = (u32)__builtin_amdgcn_readfirstlane((int)siv);
                u64 row = sbuf[cur][s][lane];
                u64 aw = rl64(act, (int)(si >> 6));
                u64 msk = 0ull - ((aw >> (si & 63u)) & 1ull);
                act &= ~(row & msk);
            }
        }
        __syncthreads();
    }
    if (wv == 0) keep[lane] = act;         // final act == keep mask
}

// K4: gated output, 16 blocks x 256 threads, coalesced (R17 exact).
__global__ void k_out(const float* __restrict__ rows,
                      const u64* __restrict__ keep,
                      float* __restrict__ out) {
    int i = blockIdx.x * 256 + threadIdx.x;
    bool kp = (keep[i >> 6] >> (i & 63)) & 1ull;
    float4 a = kp ? ((const float4*)rows)[i * 2]     : make_float4(0.f, 0.f, 0.f, 0.f);
    float4 b = kp ? ((const float4*)rows)[i * 2 + 1] : make_float4(0.f, 0.f, 0.f, 0.f);
    ((float4*)out)[i * 2]     = a;
    ((float4*)out)[i * 2 + 1] = b;
}

extern "C" void kernel_launch(void* const* d_in, const int* in_sizes, int n_in,
                              void* d_out, int out_size, void* d_ws, size_t ws_size,
                              hipStream_t stream) {
    const float* res = (const float*)d_in[0];
    float* out = (float*)d_out;

    float*  rows  = (float*)d_ws;                     // 32768 f32
    float*  ssc   = rows + N_DET * 8;                 // 4096 f32
    float4* soaLO = (float4*)(ssc + N_DET);           // 4096 float4
    float4* soaHI = soaLO + N_DET;                    // 4096 float4
    u64*    A     = (u64*)(soaHI + N_DET);            // 64 u64
    u64*    keep  = A + NW;                           // 64 u64
    u64*    Trm   = keep + NW;                        // 4096*64 u64

    k_sort<<<N_DET / 16, 256, 0, stream>>>(res, rows, ssc, soaLO, soaHI, A, Trm);
    k_sup <<<N_DET / 4, 256, 0, stream>>>(soaLO, soaHI, ssc, Trm, A);
    k_scan<<<1, 256, 0, stream>>>(Trm, A, ssc, keep);
    k_out <<<16, 256, 0, stream>>>(rows, keep, out);
}